// Round 8
// baseline (184.877 us; speedup 1.0000x reference)
//
#include <hip/hip_runtime.h>
#include <stdint.h>

#define BB 4
#define CC 64
#define HH 64
#define WW 192
#define DD 24
#define HWQ (HH * WW)            // 12288 pixels per (b) image plane
#define PIX (BB * HWQ)           // 49152 pixels total
#define PCN ((size_t)PIX * CC)   // elements per transformed array (bf16 in ws)

// ---------- bf16 helpers (workspace Q/K stored bf16 to halve traffic) ----------
__device__ __forceinline__ float bflo(uint32_t u) {
    union { uint32_t i; float f; } c; c.i = u << 16; return c.f;
}
__device__ __forceinline__ float bfhi(uint32_t u) {
    union { uint32_t i; float f; } c; c.i = u & 0xffff0000u; return c.f;
}
__device__ __forceinline__ uint16_t f2bf(float f) {  // RNE, finite inputs only
    union { float f; uint32_t i; } c; c.f = f;
    uint32_t u = c.i;
    return (uint16_t)((u + 0x7fffu + ((u >> 16) & 1u)) >> 16);
}

// =====================================================================
// Conv1x1: out[pix][o] = sum_i W[o][i]*in[i][pix] + bias[o], f32 math,
// bf16 store to ws pixel-major [b,h,w,c].
// combos: 0: x*qw -> Q1t | 1: y*kw -> K1t | 2: y*qw -> Q2t | 3: x*kw -> K2t
// grid (PIX/256, 4), block (64,4). Thread = 4 consecutive pixels x 16 o-chunk.
// =====================================================================
__global__ __launch_bounds__(256) void conv_kernel(
    const float* __restrict__ x, const float* __restrict__ y,
    const float* __restrict__ qw, const float* __restrict__ qb,
    const float* __restrict__ kw, const float* __restrict__ kb,
    uint16_t* __restrict__ ws) {
    const int combo = blockIdx.y;
    const float* src = (combo == 0 || combo == 3) ? x : y;
    const float* wgt = (combo == 0 || combo == 2) ? qw : kw;
    const float* bia = (combo == 0 || combo == 2) ? qb : kb;
    uint16_t* dst = ws + (size_t)combo * PCN;

    __shared__ float wt[64][64];   // wt[i][o] = W[o][i] (transposed)
    __shared__ float bs[64];
    const int tid = threadIdx.y * 64 + threadIdx.x;
    for (int idx = tid; idx < 4096; idx += 256) {
        int o = idx >> 6, i = idx & 63;
        wt[i][o] = wgt[idx];
    }
    if (tid < 64) bs[tid] = bia[tid];
    __syncthreads();

    const int pix0 = blockIdx.x * 256 + threadIdx.x * 4;  // 4 consecutive pixels
    const int b    = pix0 / HWQ;                          // block fully within one batch
    const int hw0  = pix0 - b * HWQ;
    const int o0   = threadIdx.y * 16;

    float acc[4][16];
#pragma unroll
    for (int p = 0; p < 4; p++)
#pragma unroll
        for (int k = 0; k < 16; k++) acc[p][k] = bs[o0 + k];

    const float* sp = src + (size_t)b * CC * HWQ + hw0;
#pragma unroll 4
    for (int i = 0; i < 64; i++) {
        float4 raw = *reinterpret_cast<const float4*>(sp + (size_t)i * HWQ);
        const float* wr = &wt[i][o0];   // wave-uniform -> LDS broadcast
#pragma unroll
        for (int k = 0; k < 16; k++) {
            float wv = wr[k];
            acc[0][k] = fmaf(raw.x, wv, acc[0][k]);
            acc[1][k] = fmaf(raw.y, wv, acc[1][k]);
            acc[2][k] = fmaf(raw.z, wv, acc[2][k]);
            acc[3][k] = fmaf(raw.w, wv, acc[3][k]);
        }
    }

#pragma unroll
    for (int p = 0; p < 4; p++) {
        uint32_t pk[8];
#pragma unroll
        for (int k = 0; k < 8; k++)
            pk[k] = (uint32_t)f2bf(acc[p][2 * k]) | ((uint32_t)f2bf(acc[p][2 * k + 1]) << 16);
        uint16_t* dp = dst + (size_t)(pix0 + p) * CC + o0;   // 32B-aligned
        uint4 lo; lo.x = pk[0]; lo.y = pk[1]; lo.z = pk[2]; lo.w = pk[3];
        uint4 hi; hi.x = pk[4]; hi.y = pk[5]; hi.z = pk[6]; hi.w = pk[7];
        *reinterpret_cast<uint4*>(dp)     = lo;
        *reinterpret_cast<uint4*>(dp + 8) = hi;
    }
}

// =====================================================================
// Cost volume, f32 math, F32 OUTPUT. One block per (h, b, v). Both K rows
// (y0,y1 fixed by h) staged in LDS bf16 (stride 68 ushorts to break bank
// aliasing). 16 lanes per output (4 ch each), shfl reduce, float store.
// grid (HH, BB, 2), block 1024.
// =====================================================================
__global__ __launch_bounds__(1024) void cost_kernel(
    const float* __restrict__ disp1, const float* __restrict__ disp2,
    const uint16_t* __restrict__ ws, float* __restrict__ out) {
    const int h = blockIdx.x;
    const int b = blockIdx.y;
    const int v = blockIdx.z;

    const uint16_t* Q    = ws + (size_t)(v ? 2 : 0) * PCN;
    const uint16_t* K    = ws + (size_t)(v ? 3 : 1) * PCN;
    const float*    disp = v ? disp2 : disp1;

    // ---- row geometry — uniform for the whole block ----
    const float ys  = (float)h * (float)(64.0 / 63.0) - 0.5f;
    const float y0f = floorf(ys);
    const float ty  = ys - y0f;
    const int   y0  = (int)y0f;
    const int   y1  = y0 + 1;
    const float vy0 = (y0 >= 0 && y0 < HH) ? 1.f : 0.f;
    const float vy1 = (y1 >= 0 && y1 < HH) ? 1.f : 0.f;
    const int   y0c = min(max(y0, 0), HH - 1);
    const int   y1c = min(max(y1, 0), HH - 1);
    const float ey0 = (1.f - ty) * vy0;
    const float ey1 = ty * vy1;

    __shared__ uint16_t krows[2][WW * 68];   // 52,224 B
    {
        const uint16_t* kr0 = K + ((size_t)b * HH + y0c) * WW * CC;
        const uint16_t* kr1 = K + ((size_t)b * HH + y1c) * WW * CC;
        for (int idx = threadIdx.x; idx < 2 * WW * 16; idx += 1024) {
            int r   = (idx >= WW * 16) ? 1 : 0;
            int k2  = idx - r * (WW * 16);
            int xx  = k2 >> 4;
            int cgi = k2 & 15;
            uint2 val = *reinterpret_cast<const uint2*>((r ? kr1 : kr0) + xx * CC + cgi * 4);
            *reinterpret_cast<uint2*>(&krows[r][xx * 68 + cgi * 4]) = val;
        }
    }
    __syncthreads();

    const int tid = threadIdx.x;
    const int cg  = tid & 15;   // channel group: channels 4cg..4cg+3
    const int jj  = tid >> 4;   // 0..63: which w within chunk

    const float cx = (float)(192.0 / 191.0);
    const float inv_c = 1.f / 64.f;

#pragma unroll
    for (int wc = 0; wc < 3; wc++) {
        const int w = wc * 64 + jj;
        // Q vector for (b,h,w) — constant across d
        const uint2 qraw = *reinterpret_cast<const uint2*>(
            Q + ((size_t)b * HWQ + h * WW + w) * CC + cg * 4);
        const float q0 = bflo(qraw.x), q1 = bfhi(qraw.x);
        const float q2 = bflo(qraw.y), q3 = bfhi(qraw.y);

        const float* dp = disp + (size_t)b * DD * HWQ + h * WW + w;
        float*       op = out + ((size_t)(v * BB + b) * DD) * HWQ + h * WW + w;

        for (int d = 0; d < DD; d++) {
            const float xs  = dp[(size_t)d * HWQ] * cx - 0.5f;
            const float x0f = floorf(xs);
            const float tx  = xs - x0f;
            const int   x0  = (int)x0f;
            const int   x1  = x0 + 1;
            const float vx0 = (x0 >= 0 && x0 < WW) ? 1.f : 0.f;
            const float vx1 = (x1 >= 0 && x1 < WW) ? 1.f : 0.f;
            const int   x0c = min(max(x0, 0), WW - 1);
            const int   x1c = min(max(x1, 0), WW - 1);
            const float w00 = ey0 * (1.f - tx) * vx0;
            const float w01 = ey0 * tx * vx1;
            const float w10 = ey1 * (1.f - tx) * vx0;
            const float w11 = ey1 * tx * vx1;

            const uint2 k00 = *reinterpret_cast<const uint2*>(&krows[0][x0c * 68 + cg * 4]);
            const uint2 k01 = *reinterpret_cast<const uint2*>(&krows[0][x1c * 68 + cg * 4]);
            const uint2 k10 = *reinterpret_cast<const uint2*>(&krows[1][x0c * 68 + cg * 4]);
            const uint2 k11 = *reinterpret_cast<const uint2*>(&krows[1][x1c * 68 + cg * 4]);

            float g0 = w00 * bflo(k00.x) + w01 * bflo(k01.x) + w10 * bflo(k10.x) + w11 * bflo(k11.x);
            float g1 = w00 * bfhi(k00.x) + w01 * bfhi(k01.x) + w10 * bfhi(k10.x) + w11 * bfhi(k11.x);
            float g2 = w00 * bflo(k00.y) + w01 * bflo(k01.y) + w10 * bflo(k10.y) + w11 * bflo(k11.y);
            float g3 = w00 * bfhi(k00.y) + w01 * bfhi(k01.y) + w10 * bfhi(k10.y) + w11 * bfhi(k11.y);

            float s = q0 * g0 + q1 * g1 + q2 * g2 + q3 * g3;
            s += __shfl_xor(s, 8);
            s += __shfl_xor(s, 4);
            s += __shfl_xor(s, 2);
            s += __shfl_xor(s, 1);
            if (cg == 0) op[(size_t)d * HWQ] = s * inv_c;   // F32 STORE
        }
    }
}

// =====================================================================
extern "C" void kernel_launch(void* const* d_in, const int* in_sizes, int n_in,
                              void* d_out, int out_size, void* d_ws, size_t ws_size,
                              hipStream_t stream) {
    const float* x  = (const float*)d_in[0];
    const float* y  = (const float*)d_in[1];
    const float* d1 = (const float*)d_in[2];
    const float* d2 = (const float*)d_in[3];
    // d_in[4] = ndisp (int32) — compile-time DD=24
    const float* qw = (const float*)d_in[5];
    const float* qb = (const float*)d_in[6];
    const float* kw = (const float*)d_in[7];
    const float* kb = (const float*)d_in[8];

    uint16_t* ws  = (uint16_t*)d_ws;   // 4 x [49152 x 64] bf16 = 25.2 MB
    float*    out = (float*)d_out;     // f32: the reference's output dtype

    conv_kernel<<<dim3(PIX / 256, 4), dim3(64, 4), 0, stream>>>(x, y, qw, qb, kw, kb, ws);
    cost_kernel<<<dim3(HH, BB, 2), dim3(1024), 0, stream>>>(d1, d2, ws, out);
}

// Round 9
// 169.907 us; speedup vs baseline: 1.0881x; 1.0881x over previous
//
#include <hip/hip_runtime.h>
#include <stdint.h>

#define BB 4
#define CC 64
#define HH 64
#define WW 192
#define DD 24
#define HWQ (HH * WW)            // 12288 pixels per image plane
#define PIX (BB * HWQ)           // 49152 pixels per volume side

typedef __attribute__((ext_vector_type(8))) short short8;
typedef __attribute__((ext_vector_type(4))) float floatx4;

// ---------- bf16 helpers ----------
__device__ __forceinline__ float bf1(uint16_t u) {
    union { uint32_t i; float f; } c; c.i = ((uint32_t)u) << 16; return c.f;
}
__device__ __forceinline__ uint16_t f2bf(float f) {  // RNE, finite inputs only
    union { float f; uint32_t i; } c; c.f = f;
    uint32_t u = c.i;
    return (uint16_t)((u + 0x7fffu + ((u >> 16) & 1u)) >> 16);
}

// ws layout (shorts from base):
//   A:  [2][PIX][CC] bf16                  (6,291,456 shorts = 12.58 MB)
//   f32 region (cast at short offset 6291456):
//     G[4096], beta[64], alpha[64], gamma[1], pad..., s[2*PIX] (at f32 idx 4240)
#define A_SHORTS ((size_t)2 * PIX * CC)
#define S_F32OFF 4240

// =====================================================================
// Prep: G[i][j] = sum_c qw[c,i]*kw[c,j]; beta[j] = sum_c qb[c]*kw[c,j];
// alpha[i] = sum_c qw[c,i]*kb[c]; gamma = qb.kb.  One block, 256 threads.
// =====================================================================
__global__ __launch_bounds__(256) void prep_kernel(
    const float* __restrict__ qw, const float* __restrict__ qb,
    const float* __restrict__ kw, const float* __restrict__ kb,
    float* __restrict__ fws) {
    float* G     = fws;
    float* beta  = fws + 4096;
    float* alpha = fws + 4160;
    float* gamma = fws + 4224;
    const int t = threadIdx.x;
    for (int idx = t; idx < 4096; idx += 256) {
        const int i = idx >> 6, j = idx & 63;
        float acc = 0.f;
        for (int c = 0; c < CC; c++) acc = fmaf(qw[c * CC + i], kw[c * CC + j], acc);
        G[idx] = acc;
    }
    if (t < 64) {
        float bt = 0.f, al = 0.f;
        for (int c = 0; c < CC; c++) {
            bt = fmaf(qb[c], kw[c * CC + t], bt);
            al = fmaf(qw[c * CC + t], kb[c], al);
        }
        beta[t] = bt; alpha[t] = al;
    }
    if (t == 64) {
        float g = 0.f;
        for (int c = 0; c < CC; c++) g = fmaf(qb[c], kb[c], g);
        *gamma = g;
    }
}

// =====================================================================
// convA: A[v][pix][j] = bf16( sum_i G[i][j]*X_i + beta[j] ),
//        s[v][pix]    = sum_i alpha[i]*X_i + gamma   (f32)
// v=0: X=x, v=1: X=y.  grid (PIX/256, 2), block (64,4).
// =====================================================================
__global__ __launch_bounds__(256) void convA_kernel(
    const float* __restrict__ x, const float* __restrict__ y,
    const float* __restrict__ fws, uint16_t* __restrict__ A) {
    const int v = blockIdx.y;
    const float* src = v ? y : x;
    const float* G     = fws;
    const float* beta  = fws + 4096;
    const float* alpha = fws + 4160;
    const float* gamma = fws + 4224;
    float* s = const_cast<float*>(fws) + S_F32OFF;

    __shared__ float wt[64][64];   // wt[i][j] = G[i][j]
    __shared__ float bs[64], al[64];
    __shared__ float gm;
    const int tid = threadIdx.y * 64 + threadIdx.x;
    for (int idx = tid; idx < 4096; idx += 256) wt[idx >> 6][idx & 63] = G[idx];
    if (tid < 64) { bs[tid] = beta[tid]; al[tid] = alpha[tid]; }
    if (tid == 64) gm = *gamma;
    __syncthreads();

    const int pix0 = blockIdx.x * 256 + threadIdx.x * 4;
    const int b    = pix0 / HWQ;
    const int hw0  = pix0 - b * HWQ;
    const int j0   = threadIdx.y * 16;

    float acc[4][16];
#pragma unroll
    for (int p = 0; p < 4; p++)
#pragma unroll
        for (int k = 0; k < 16; k++) acc[p][k] = bs[j0 + k];
    float sac[4] = {gm, gm, gm, gm};

    const float* sp = src + (size_t)b * CC * HWQ + hw0;
#pragma unroll 4
    for (int i = 0; i < 64; i++) {
        float4 raw = *reinterpret_cast<const float4*>(sp + (size_t)i * HWQ);
        const float* wr = &wt[i][j0];   // wave-uniform -> LDS broadcast
        const float av = al[i];
        sac[0] = fmaf(raw.x, av, sac[0]);
        sac[1] = fmaf(raw.y, av, sac[1]);
        sac[2] = fmaf(raw.z, av, sac[2]);
        sac[3] = fmaf(raw.w, av, sac[3]);
#pragma unroll
        for (int k = 0; k < 16; k++) {
            float wv = wr[k];
            acc[0][k] = fmaf(raw.x, wv, acc[0][k]);
            acc[1][k] = fmaf(raw.y, wv, acc[1][k]);
            acc[2][k] = fmaf(raw.z, wv, acc[2][k]);
            acc[3][k] = fmaf(raw.w, wv, acc[3][k]);
        }
    }

    uint16_t* dstv = A + (size_t)v * PIX * CC;
#pragma unroll
    for (int p = 0; p < 4; p++) {
        uint32_t pk[8];
#pragma unroll
        for (int k = 0; k < 8; k++)
            pk[k] = (uint32_t)f2bf(acc[p][2 * k]) | ((uint32_t)f2bf(acc[p][2 * k + 1]) << 16);
        uint16_t* dp = dstv + (size_t)(pix0 + p) * CC + j0;
        uint4 lo; lo.x = pk[0]; lo.y = pk[1]; lo.z = pk[2]; lo.w = pk[3];
        uint4 hi; hi.x = pk[4]; hi.y = pk[5]; hi.z = pk[6]; hi.w = pk[7];
        *reinterpret_cast<uint4*>(dp)     = lo;
        *reinterpret_cast<uint4*>(dp + 8) = hi;
    }
    if (threadIdx.y == 0) {
        float4 sv; sv.x = sac[0]; sv.y = sac[1]; sv.z = sac[2]; sv.w = sac[3];
        *reinterpret_cast<float4*>(s + (size_t)v * PIX + pix0) = sv;
    }
}

// =====================================================================
// Cost: per block (h,b,v). Stage raw Y rows (y0c,y1c) to LDS bf16
// [R=r*192+x'][c] stride 68. For each 16-wide w-chunk: MFMA
// P[w][R] = A_w . Y_R  (M=16,N=384,K=64; bf16 in, f32 acc, bf16 P in LDS),
// then epilogue: out = (w00*P00+w01*P01+w10*P10+w11*P11 + s_w*sumw)/64.
// grid (HH, BB, 2), block 1024 (16 waves).
// =====================================================================
__global__ __launch_bounds__(1024) void cost_kernel(
    const float* __restrict__ x, const float* __restrict__ y,
    const float* __restrict__ disp1, const float* __restrict__ disp2,
    const uint16_t* __restrict__ A, const float* __restrict__ fws,
    float* __restrict__ out) {
    const int h = blockIdx.x;
    const int b = blockIdx.y;
    const int v = blockIdx.z;

    const float*    Yv   = v ? x : y;          // gathered (raw) source
    const float*    disp = v ? disp2 : disp1;
    const uint16_t* Ab   = A + ((size_t)v * PIX + (size_t)b * HWQ + h * WW) * CC;
    const float*    sb   = fws + S_F32OFF + (size_t)v * PIX + (size_t)b * HWQ + h * WW;

    // ---- row geometry (uniform) ----
    const float ys  = (float)h * (float)(64.0 / 63.0) - 0.5f;
    const float y0f = floorf(ys);
    const float ty  = ys - y0f;
    const int   y0  = (int)y0f;
    const int   y1  = y0 + 1;
    const float vy0 = (y0 >= 0 && y0 < HH) ? 1.f : 0.f;
    const float vy1 = (y1 >= 0 && y1 < HH) ? 1.f : 0.f;
    const int   y0c = min(max(y0, 0), HH - 1);
    const int   y1c = min(max(y1, 0), HH - 1);
    const float ey0 = (1.f - ty) * vy0;
    const float ey1 = ty * vy1;

    __shared__ uint16_t Yt[384 * 68];   // 52,224 B: [R][c], stride 68
    __shared__ uint16_t Pt[16 * 392];   // 12,544 B: [w_local][R], stride 392

    const int tid = threadIdx.x;

    // ---- stage Y rows: Yt[(r*192+x)][c] = bf16(Yv[b][c][y_rc][x]) ----
    for (int idx = tid; idx < 2 * 64 * 48; idx += 1024) {
        const int r   = idx / 3072;
        const int rem = idx - r * 3072;
        const int c   = rem / 48;
        const int x0  = (rem - c * 48) * 4;
        const int row = r ? y1c : y0c;
        float4 vv = *reinterpret_cast<const float4*>(
            Yv + (((size_t)(b * CC + c) * HH + row) * WW + x0));
        const int base = (r * 192 + x0) * 68 + c;
        Yt[base]       = f2bf(vv.x);
        Yt[base + 68]  = f2bf(vv.y);
        Yt[base + 136] = f2bf(vv.z);
        Yt[base + 204] = f2bf(vv.w);
    }
    __syncthreads();

    const int wave = tid >> 6;
    const int lane = tid & 63;
    const int lq   = lane >> 4;    // quad 0..3
    const int ln   = lane & 15;

    const float cx = (float)(192.0 / 191.0);
    const float inv_c = 1.f / 64.f;

    for (int wc = 0; wc < 12; wc++) {
        const int wbase = wc * 16;
        // --- MFMA phase: A-frag A[m=ln][k=lq*8+j] from global (bf16 pixel-major) ---
        const uint16_t* arow = Ab + (size_t)(wbase + ln) * CC + lq * 8;
        short8 a0 = *reinterpret_cast<const short8*>(arow);        // c 0..31
        short8 a1 = *reinterpret_cast<const short8*>(arow + 32);   // c 32..63
        for (int t = wave; t < 24; t += 16) {
            const int R0 = t * 16 + ln;     // B col n = ln
            const int cb = lq * 8;          // B row k = lq*8+j
            short8 b0, b1;
            *reinterpret_cast<uint2*>(&b0)     = *reinterpret_cast<const uint2*>(&Yt[R0 * 68 + cb]);
            *(reinterpret_cast<uint2*>(&b0)+1) = *reinterpret_cast<const uint2*>(&Yt[R0 * 68 + cb + 4]);
            *reinterpret_cast<uint2*>(&b1)     = *reinterpret_cast<const uint2*>(&Yt[R0 * 68 + 32 + cb]);
            *(reinterpret_cast<uint2*>(&b1)+1) = *reinterpret_cast<const uint2*>(&Yt[R0 * 68 + 32 + cb + 4]);
            floatx4 acc = {0.f, 0.f, 0.f, 0.f};
            acc = __builtin_amdgcn_mfma_f32_16x16x32_bf16(a0, b0, acc, 0, 0, 0);
            acc = __builtin_amdgcn_mfma_f32_16x16x32_bf16(a1, b1, acc, 0, 0, 0);
            // C layout: col = ln (R), row = lq*4 + reg (w_local)
            const int pcol = t * 16 + ln;
            Pt[(lq * 4 + 0) * 392 + pcol] = f2bf(acc[0]);
            Pt[(lq * 4 + 1) * 392 + pcol] = f2bf(acc[1]);
            Pt[(lq * 4 + 2) * 392 + pcol] = f2bf(acc[2]);
            Pt[(lq * 4 + 3) * 392 + pcol] = f2bf(acc[3]);
        }
        __syncthreads();
        // --- epilogue: 16 w x 24 d outputs ---
        for (int o = tid; o < 16 * DD; o += 1024) {
            const int wl = o & 15;
            const int d  = o >> 4;
            const int w  = wbase + wl;
            const float dsv = disp[((size_t)(b * DD + d) * HH + h) * WW + w];
            const float xs  = dsv * cx - 0.5f;
            const float x0f = floorf(xs);
            const float tx  = xs - x0f;
            const int   x0  = (int)x0f;
            const int   x1  = x0 + 1;
            const float vx0 = (x0 >= 0 && x0 < WW) ? 1.f : 0.f;
            const float vx1 = (x1 >= 0 && x1 < WW) ? 1.f : 0.f;
            const int   x0c = min(max(x0, 0), WW - 1);
            const int   x1c = min(max(x1, 0), WW - 1);
            const float w00 = ey0 * (1.f - tx) * vx0;
            const float w01 = ey0 * tx * vx1;
            const float w10 = ey1 * (1.f - tx) * vx0;
            const float w11 = ey1 * tx * vx1;
            const float P00 = bf1(Pt[wl * 392 + x0c]);
            const float P01 = bf1(Pt[wl * 392 + x1c]);
            const float P10 = bf1(Pt[wl * 392 + 192 + x0c]);
            const float P11 = bf1(Pt[wl * 392 + 192 + x1c]);
            const float sw  = sb[w];
            const float res = w00 * P00 + w01 * P01 + w10 * P10 + w11 * P11
                            + sw * (w00 + w01 + w10 + w11);
            out[(((size_t)(v * BB + b) * DD + d) * HH + h) * WW + w] = res * inv_c;
        }
        __syncthreads();
    }
}

// =====================================================================
extern "C" void kernel_launch(void* const* d_in, const int* in_sizes, int n_in,
                              void* d_out, int out_size, void* d_ws, size_t ws_size,
                              hipStream_t stream) {
    const float* x  = (const float*)d_in[0];
    const float* y  = (const float*)d_in[1];
    const float* d1 = (const float*)d_in[2];
    const float* d2 = (const float*)d_in[3];
    // d_in[4] = ndisp (int32) — compile-time DD=24
    const float* qw = (const float*)d_in[5];
    const float* qb = (const float*)d_in[6];
    const float* kw = (const float*)d_in[7];
    const float* kb = (const float*)d_in[8];

    uint16_t* A   = (uint16_t*)d_ws;
    float*    fws = (float*)((uint16_t*)d_ws + A_SHORTS);
    float*    out = (float*)d_out;

    prep_kernel<<<dim3(1), dim3(256), 0, stream>>>(qw, qb, kw, kb, fws);
    convA_kernel<<<dim3(PIX / 256, 2), dim3(64, 4), 0, stream>>>(x, y, fws, A);
    cost_kernel<<<dim3(HH, BB, 2), dim3(1024), 0, stream>>>(x, y, d1, d2, A, fws, out);
}

// Round 10
// 138.503 us; speedup vs baseline: 1.3348x; 1.2267x over previous
//
#include <hip/hip_runtime.h>
#include <stdint.h>

#define BB 4
#define CC 64
#define HH 64
#define WW 192
#define DD 24
#define HWQ (HH * WW)            // 12288 pixels per image plane
#define PIX (BB * HWQ)           // 49152 pixels per volume side

typedef __attribute__((ext_vector_type(8))) short short8;
typedef __attribute__((ext_vector_type(4))) float floatx4;

// ---------- bf16 helpers ----------
__device__ __forceinline__ float bf1(uint16_t u) {
    union { uint32_t i; float f; } c; c.i = ((uint32_t)u) << 16; return c.f;
}
__device__ __forceinline__ uint16_t f2bf(float f) {  // RNE, finite inputs only
    union { float f; uint32_t i; } c; c.f = f;
    uint32_t u = c.i;
    return (uint16_t)((u + 0x7fffu + ((u >> 16) & 1u)) >> 16);
}

// ws layout (shorts from base):
//   A: [2][PIX][CC] bf16; then f32 region: G[4096], beta[64], alpha[64],
//   gamma[1], pad, s[2*PIX] at f32 idx 4240.
#define A_SHORTS ((size_t)2 * PIX * CC)
#define S_F32OFF 4240

// =====================================================================
// Prep (parallel): blocks 0..63: G[i][j] = sum_c qw[c,i]*kw[c,j]
// block 64: beta[j] = sum_c qb[c]*kw[c,j] (+gamma on t0); block 65: alpha.
// grid 66, block 64.
// =====================================================================
__global__ __launch_bounds__(64) void prep_kernel(
    const float* __restrict__ qw, const float* __restrict__ qb,
    const float* __restrict__ kw, const float* __restrict__ kb,
    float* __restrict__ fws) {
    const int bid = blockIdx.x;
    const int j   = threadIdx.x;
    if (bid < 64) {
        float acc = 0.f;
        for (int c = 0; c < CC; c++)
            acc = fmaf(qw[c * CC + bid], kw[c * CC + j], acc);  // qw read is wave-uniform
        fws[bid * 64 + j] = acc;
    } else if (bid == 64) {
        float bt = 0.f;
        for (int c = 0; c < CC; c++) bt = fmaf(qb[c], kw[c * CC + j], bt);
        fws[4096 + j] = bt;
        if (j == 0) {
            float g = 0.f;
            for (int c = 0; c < CC; c++) g = fmaf(qb[c], kb[c], g);
            fws[4224] = g;
        }
    } else {
        float al = 0.f;
        for (int c = 0; c < CC; c++) al = fmaf(qw[c * CC + j], kb[c], al);
        fws[4160 + j] = al;
    }
}

// =====================================================================
// convA: A[v][pix][j] = bf16( sum_i G[i][j]*X_i + beta[j] ),
//        s[v][pix]    = sum_i alpha[i]*X_i + gamma   (f32)
// v=0: X=x, v=1: X=y.  grid (PIX/256, 2), block (64,4).
// =====================================================================
__global__ __launch_bounds__(256) void convA_kernel(
    const float* __restrict__ x, const float* __restrict__ y,
    const float* __restrict__ fws, uint16_t* __restrict__ A) {
    const int v = blockIdx.y;
    const float* src = v ? y : x;
    const float* G     = fws;
    const float* beta  = fws + 4096;
    const float* alpha = fws + 4160;
    const float* gamma = fws + 4224;
    float* s = const_cast<float*>(fws) + S_F32OFF;

    __shared__ float wt[64][64];   // wt[i][j] = G[i][j]
    __shared__ float bs[64], al[64];
    __shared__ float gm;
    const int tid = threadIdx.y * 64 + threadIdx.x;
    for (int idx = tid; idx < 4096; idx += 256) wt[idx >> 6][idx & 63] = G[idx];
    if (tid < 64) { bs[tid] = beta[tid]; al[tid] = alpha[tid]; }
    if (tid == 64) gm = *gamma;
    __syncthreads();

    const int pix0 = blockIdx.x * 256 + threadIdx.x * 4;
    const int b    = pix0 / HWQ;
    const int hw0  = pix0 - b * HWQ;
    const int j0   = threadIdx.y * 16;

    float acc[4][16];
#pragma unroll
    for (int p = 0; p < 4; p++)
#pragma unroll
        for (int k = 0; k < 16; k++) acc[p][k] = bs[j0 + k];
    float sac[4] = {gm, gm, gm, gm};

    const float* sp = src + (size_t)b * CC * HWQ + hw0;
#pragma unroll 4
    for (int i = 0; i < 64; i++) {
        float4 raw = *reinterpret_cast<const float4*>(sp + (size_t)i * HWQ);
        const float* wr = &wt[i][j0];   // wave-uniform -> LDS broadcast
        const float av = al[i];
        sac[0] = fmaf(raw.x, av, sac[0]);
        sac[1] = fmaf(raw.y, av, sac[1]);
        sac[2] = fmaf(raw.z, av, sac[2]);
        sac[3] = fmaf(raw.w, av, sac[3]);
#pragma unroll
        for (int k = 0; k < 16; k++) {
            float wv = wr[k];
            acc[0][k] = fmaf(raw.x, wv, acc[0][k]);
            acc[1][k] = fmaf(raw.y, wv, acc[1][k]);
            acc[2][k] = fmaf(raw.z, wv, acc[2][k]);
            acc[3][k] = fmaf(raw.w, wv, acc[3][k]);
        }
    }

    uint16_t* dstv = A + (size_t)v * PIX * CC;
#pragma unroll
    for (int p = 0; p < 4; p++) {
        uint32_t pk[8];
#pragma unroll
        for (int k = 0; k < 8; k++)
            pk[k] = (uint32_t)f2bf(acc[p][2 * k]) | ((uint32_t)f2bf(acc[p][2 * k + 1]) << 16);
        uint16_t* dp = dstv + (size_t)(pix0 + p) * CC + j0;
        uint4 lo; lo.x = pk[0]; lo.y = pk[1]; lo.z = pk[2]; lo.w = pk[3];
        uint4 hi; hi.x = pk[4]; hi.y = pk[5]; hi.z = pk[6]; hi.w = pk[7];
        *reinterpret_cast<uint4*>(dp)     = lo;
        *reinterpret_cast<uint4*>(dp + 8) = hi;
    }
    if (threadIdx.y == 0) {
        float4 sv; sv.x = sac[0]; sv.y = sac[1]; sv.z = sac[2]; sv.w = sac[3];
        *reinterpret_cast<float4*>(s + (size_t)v * PIX + pix0) = sv;
    }
}

// =====================================================================
// Cost: block per (h, b, v, w-quarter). Bilinear Y-row combination folded
// into the MFMA B-operand: Yc[x][c] = bf16(ey0*Y[y0c] + ey1*Y[y1c]).
// PC[w][x'] = A_w . Yc[x']  (M=16 per chunk, 3 chunks, N=192, K=64).
// Epilogue: out = ((1-tx)*vx0*PC[x0c] + tx*vx1*PC[x1c] + s_w*sumw)/64.
// ONE barrier pair per block. grid (HH, BB, 8), block 256 (4 waves).
// =====================================================================
__global__ __launch_bounds__(256) void cost_kernel(
    const float* __restrict__ x, const float* __restrict__ y,
    const float* __restrict__ disp1, const float* __restrict__ disp2,
    const uint16_t* __restrict__ A, const float* __restrict__ fws,
    float* __restrict__ out) {
    const int h   = blockIdx.x;
    const int b   = blockIdx.y;
    const int v   = blockIdx.z >> 2;
    const int qtr = blockIdx.z & 3;
    const int w0  = qtr * 48;

    const float*    Yv   = v ? x : y;          // gathered (raw) source
    const float*    disp = v ? disp2 : disp1;
    const uint16_t* Ab   = A + ((size_t)v * PIX + (size_t)b * HWQ + h * WW + w0) * CC;
    const float*    sb   = fws + S_F32OFF + (size_t)v * PIX + (size_t)b * HWQ + h * WW + w0;

    // ---- row geometry (uniform) ----
    const float ys  = (float)h * (float)(64.0 / 63.0) - 0.5f;
    const float y0f = floorf(ys);
    const float ty  = ys - y0f;
    const int   y0  = (int)y0f;
    const int   y1  = y0 + 1;
    const float vy0 = (y0 >= 0 && y0 < HH) ? 1.f : 0.f;
    const float vy1 = (y1 >= 0 && y1 < HH) ? 1.f : 0.f;
    const int   y0c = min(max(y0, 0), HH - 1);
    const int   y1c = min(max(y1, 0), HH - 1);
    const float ey0 = (1.f - ty) * vy0;
    const float ey1 = ty * vy1;
    const float eysum = ey0 + ey1;

    __shared__ uint16_t Yc[192 * 68];   // 26,112 B: combined row, [x][c] stride 68
    __shared__ uint16_t Pt[48 * 196];   // 18,816 B: [w_local][x] stride 196

    const int tid  = threadIdx.x;
    const int wave = tid >> 6;
    const int lane = tid & 63;
    const int lq   = lane >> 4;    // quad 0..3
    const int ln   = lane & 15;

    // ---- prefetch A-frags for chunk 0 (hidden behind staging) ----
    const uint16_t* ar0 = Ab + (size_t)ln * CC + lq * 8;
    short8 a0 = *reinterpret_cast<const short8*>(ar0);
    short8 a1 = *reinterpret_cast<const short8*>(ar0 + 32);

    // ---- stage Yc: 12 iters; per iter: c-chunk cg = wave+4*(k%4) (wave-
    // uniform), x = (k/4)*64 + lane. Coalesced 256B global runs per c. ----
    const float* Yb0 = Yv + ((size_t)b * CC * HH + y0c) * WW;
    const float* Yb1 = Yv + ((size_t)b * CC * HH + y1c) * WW;
#pragma unroll
    for (int k = 0; k < 12; k++) {
        const int cg = wave + 4 * (k & 3);
        const int xx = (k >> 2) * 64 + lane;
        uint32_t pk[2];
#pragma unroll
        for (int half = 0; half < 2; half++) {
            uint32_t pv = 0;
#pragma unroll
            for (int j = 0; j < 2; j++) {
                const int c = cg * 4 + half * 2 + j;
                const float v0 = Yb0[(size_t)c * HH * WW + xx];
                const float v1 = Yb1[(size_t)c * HH * WW + xx];
                const float cb = fmaf(ey1, v1, ey0 * v0);
                pv |= ((uint32_t)f2bf(cb)) << (16 * j);
            }
            pk[half] = pv;
        }
        *reinterpret_cast<uint2*>(&Yc[xx * 68 + cg * 4]) = *reinterpret_cast<uint2*>(pk);
    }
    __syncthreads();

    // ---- MFMA phase: 3 chunks x 12 tiles; wave does 3 tiles/chunk ----
    for (int ch = 0; ch < 3; ch++) {
        short8 na0 = a0, na1 = a1;
        if (ch < 2) {
            const uint16_t* ar = Ab + (size_t)((ch + 1) * 16 + ln) * CC + lq * 8;
            na0 = *reinterpret_cast<const short8*>(ar);
            na1 = *reinterpret_cast<const short8*>(ar + 32);
        }
#pragma unroll
        for (int t3 = 0; t3 < 3; t3++) {
            const int Rb = (wave * 3 + t3) * 16;
            const uint16_t* yrow = &Yc[(Rb + ln) * 68 + lq * 8];
            short8 b0, b1;
            *reinterpret_cast<uint2*>(&b0)       = *reinterpret_cast<const uint2*>(yrow);
            *(reinterpret_cast<uint2*>(&b0) + 1) = *reinterpret_cast<const uint2*>(yrow + 4);
            *reinterpret_cast<uint2*>(&b1)       = *reinterpret_cast<const uint2*>(yrow + 32);
            *(reinterpret_cast<uint2*>(&b1) + 1) = *reinterpret_cast<const uint2*>(yrow + 36);
            floatx4 acc = {0.f, 0.f, 0.f, 0.f};
            acc = __builtin_amdgcn_mfma_f32_16x16x32_bf16(a0, b0, acc, 0, 0, 0);
            acc = __builtin_amdgcn_mfma_f32_16x16x32_bf16(a1, b1, acc, 0, 0, 0);
            // C layout: col(N)=ln -> x' ; row(M)=lq*4+reg -> w_local
            const int pcol = Rb + ln;
            const int wl   = ch * 16 + lq * 4;
            Pt[(wl + 0) * 196 + pcol] = f2bf(acc[0]);
            Pt[(wl + 1) * 196 + pcol] = f2bf(acc[1]);
            Pt[(wl + 2) * 196 + pcol] = f2bf(acc[2]);
            Pt[(wl + 3) * 196 + pcol] = f2bf(acc[3]);
        }
        a0 = na0; a1 = na1;
    }
    __syncthreads();

    // ---- epilogue: 48 w x 24 d outputs, 4.5 per thread ----
    const float cx = (float)(192.0 / 191.0);
    const float inv_c = 1.f / 64.f;
    for (int o = tid; o < 48 * DD; o += 256) {
        const int wl = o % 48;
        const int d  = o / 48;
        const int w  = w0 + wl;
        const float dsv = disp[((size_t)(b * DD + d) * HH + h) * WW + w];
        const float xs  = dsv * cx - 0.5f;
        const float x0f = floorf(xs);
        const float tx  = xs - x0f;
        const int   x0  = (int)x0f;
        const int   x1  = x0 + 1;
        const float vx0 = (x0 >= 0 && x0 < WW) ? 1.f : 0.f;
        const float vx1 = (x1 >= 0 && x1 < WW) ? 1.f : 0.f;
        const int   x0c = min(max(x0, 0), WW - 1);
        const int   x1c = min(max(x1, 0), WW - 1);
        const float wx0 = (1.f - tx) * vx0;
        const float wx1 = tx * vx1;
        const float pc0 = bf1(Pt[wl * 196 + x0c]);
        const float pc1 = bf1(Pt[wl * 196 + x1c]);
        const float res = wx0 * pc0 + wx1 * pc1 + sb[wl] * (eysum * (wx0 + wx1));
        out[(((size_t)(v * BB + b) * DD + d) * HH + h) * WW + w] = res * inv_c;
    }
}

// =====================================================================
extern "C" void kernel_launch(void* const* d_in, const int* in_sizes, int n_in,
                              void* d_out, int out_size, void* d_ws, size_t ws_size,
                              hipStream_t stream) {
    const float* x  = (const float*)d_in[0];
    const float* y  = (const float*)d_in[1];
    const float* d1 = (const float*)d_in[2];
    const float* d2 = (const float*)d_in[3];
    // d_in[4] = ndisp (int32) — compile-time DD=24
    const float* qw = (const float*)d_in[5];
    const float* qb = (const float*)d_in[6];
    const float* kw = (const float*)d_in[7];
    const float* kb = (const float*)d_in[8];

    uint16_t* A   = (uint16_t*)d_ws;
    float*    fws = (float*)((uint16_t*)d_ws + A_SHORTS);
    float*    out = (float*)d_out;

    prep_kernel<<<dim3(66), dim3(64), 0, stream>>>(qw, qb, kw, kb, fws);
    convA_kernel<<<dim3(PIX / 256, 2), dim3(64, 4), 0, stream>>>(x, y, fws, A);
    cost_kernel<<<dim3(HH, BB, 8), dim3(256), 0, stream>>>(x, y, d1, d2, A, fws, out);
}

// Round 11
// 133.543 us; speedup vs baseline: 1.3844x; 1.0371x over previous
//
#include <hip/hip_runtime.h>
#include <stdint.h>

#define BB 4
#define CC 64
#define HH 64
#define WW 192
#define DD 24
#define HWQ (HH * WW)            // 12288 pixels per image plane
#define PIX (BB * HWQ)           // 49152 pixels per volume side

typedef __attribute__((ext_vector_type(8))) short short8;
typedef __attribute__((ext_vector_type(4))) float floatx4;

// ---------- bf16 helpers ----------
__device__ __forceinline__ float bf1(uint16_t u) {
    union { uint32_t i; float f; } c; c.i = ((uint32_t)u) << 16; return c.f;
}
__device__ __forceinline__ uint16_t f2bf(float f) {  // RNE, finite inputs only
    union { float f; uint32_t i; } c; c.f = f;
    uint32_t u = c.i;
    return (uint16_t)((u + 0x7fffu + ((u >> 16) & 1u)) >> 16);
}

// ws layout (shorts from base):
//   A: [2][PIX][CC] bf16; then f32 region: G[4096], beta[64], alpha[64],
//   gamma[1], pad, s[2*PIX] at f32 idx 4240.
#define A_SHORTS ((size_t)2 * PIX * CC)
#define S_F32OFF 4240

// =====================================================================
// Prep (parallel): blocks 0..63: G[i][j] = sum_c qw[c,i]*kw[c,j]
// block 64: beta[j] = sum_c qb[c]*kw[c,j] (+gamma on t0); block 65: alpha.
// grid 66, block 64.
// =====================================================================
__global__ __launch_bounds__(64) void prep_kernel(
    const float* __restrict__ qw, const float* __restrict__ qb,
    const float* __restrict__ kw, const float* __restrict__ kb,
    float* __restrict__ fws) {
    const int bid = blockIdx.x;
    const int j   = threadIdx.x;
    if (bid < 64) {
        float acc = 0.f;
        for (int c = 0; c < CC; c++)
            acc = fmaf(qw[c * CC + bid], kw[c * CC + j], acc);  // qw read is wave-uniform
        fws[bid * 64 + j] = acc;
    } else if (bid == 64) {
        float bt = 0.f;
        for (int c = 0; c < CC; c++) bt = fmaf(qb[c], kw[c * CC + j], bt);
        fws[4096 + j] = bt;
        if (j == 0) {
            float g = 0.f;
            for (int c = 0; c < CC; c++) g = fmaf(qb[c], kb[c], g);
            fws[4224] = g;
        }
    } else {
        float al = 0.f;
        for (int c = 0; c < CC; c++) al = fmaf(qw[c * CC + j], kb[c], al);
        fws[4160 + j] = al;
    }
}

// =====================================================================
// convA: A[v][pix][j] = bf16( sum_i G[i][j]*X_i + beta[j] ),
//        s[v][pix]    = sum_i alpha[i]*X_i + gamma   (f32)
// v=0: X=x, v=1: X=y.  grid (PIX/256, 2), block (64,4).
// =====================================================================
__global__ __launch_bounds__(256) void convA_kernel(
    const float* __restrict__ x, const float* __restrict__ y,
    const float* __restrict__ fws, uint16_t* __restrict__ A) {
    const int v = blockIdx.y;
    const float* src = v ? y : x;
    const float* G     = fws;
    const float* beta  = fws + 4096;
    const float* alpha = fws + 4160;
    const float* gamma = fws + 4224;
    float* s = const_cast<float*>(fws) + S_F32OFF;

    __shared__ float wt[64][64];   // wt[i][j] = G[i][j]
    __shared__ float bs[64], al[64];
    __shared__ float gm;
    const int tid = threadIdx.y * 64 + threadIdx.x;
    for (int idx = tid; idx < 4096; idx += 256) wt[idx >> 6][idx & 63] = G[idx];
    if (tid < 64) { bs[tid] = beta[tid]; al[tid] = alpha[tid]; }
    if (tid == 64) gm = *gamma;
    __syncthreads();

    const int pix0 = blockIdx.x * 256 + threadIdx.x * 4;
    const int b    = pix0 / HWQ;
    const int hw0  = pix0 - b * HWQ;
    const int j0   = threadIdx.y * 16;

    float acc[4][16];
#pragma unroll
    for (int p = 0; p < 4; p++)
#pragma unroll
        for (int k = 0; k < 16; k++) acc[p][k] = bs[j0 + k];
    float sac[4] = {gm, gm, gm, gm};

    const float* sp = src + (size_t)b * CC * HWQ + hw0;
#pragma unroll 4
    for (int i = 0; i < 64; i++) {
        float4 raw = *reinterpret_cast<const float4*>(sp + (size_t)i * HWQ);
        const float* wr = &wt[i][j0];   // wave-uniform -> LDS broadcast
        const float av = al[i];
        sac[0] = fmaf(raw.x, av, sac[0]);
        sac[1] = fmaf(raw.y, av, sac[1]);
        sac[2] = fmaf(raw.z, av, sac[2]);
        sac[3] = fmaf(raw.w, av, sac[3]);
#pragma unroll
        for (int k = 0; k < 16; k++) {
            float wv = wr[k];
            acc[0][k] = fmaf(raw.x, wv, acc[0][k]);
            acc[1][k] = fmaf(raw.y, wv, acc[1][k]);
            acc[2][k] = fmaf(raw.z, wv, acc[2][k]);
            acc[3][k] = fmaf(raw.w, wv, acc[3][k]);
        }
    }

    uint16_t* dstv = A + (size_t)v * PIX * CC;
#pragma unroll
    for (int p = 0; p < 4; p++) {
        uint32_t pk[8];
#pragma unroll
        for (int k = 0; k < 8; k++)
            pk[k] = (uint32_t)f2bf(acc[p][2 * k]) | ((uint32_t)f2bf(acc[p][2 * k + 1]) << 16);
        uint16_t* dp = dstv + (size_t)(pix0 + p) * CC + j0;
        uint4 lo; lo.x = pk[0]; lo.y = pk[1]; lo.z = pk[2]; lo.w = pk[3];
        uint4 hi; hi.x = pk[4]; hi.y = pk[5]; hi.z = pk[6]; hi.w = pk[7];
        *reinterpret_cast<uint4*>(dp)     = lo;
        *reinterpret_cast<uint4*>(dp + 8) = hi;
    }
    if (threadIdx.y == 0) {
        float4 sv; sv.x = sac[0]; sv.y = sac[1]; sv.z = sac[2]; sv.w = sac[3];
        *reinterpret_cast<float4*>(s + (size_t)v * PIX + pix0) = sv;
    }
}

// =====================================================================
// Cost: ONE block per (h, b, v), 1024 threads (16 waves). Stage the
// bilinear-combined Y row ONCE: Yc[x][c] = bf16(ey0*Y[y0c] + ey1*Y[y1c]).
// Then two 96-w halves: 12 waves x 6 MFMA tiles (M=96,N=192,K=64 per half)
// -> Pt, barrier, epilogue. Static LDS 63.7 KB -> 2 blocks/CU.
// grid (HH, BB, 2), block 1024.
// =====================================================================
__global__ __launch_bounds__(1024) void cost_kernel(
    const float* __restrict__ x, const float* __restrict__ y,
    const float* __restrict__ disp1, const float* __restrict__ disp2,
    const uint16_t* __restrict__ A, const float* __restrict__ fws,
    float* __restrict__ out) {
    const int h = blockIdx.x;
    const int b = blockIdx.y;
    const int v = blockIdx.z;

    const float*    Yv   = v ? x : y;          // gathered (raw) source
    const float*    disp = v ? disp2 : disp1;
    const uint16_t* Ab   = A + ((size_t)v * PIX + (size_t)b * HWQ + h * WW) * CC;
    const float*    sb   = fws + S_F32OFF + (size_t)v * PIX + (size_t)b * HWQ + h * WW;

    // ---- row geometry (uniform) ----
    const float ys  = (float)h * (float)(64.0 / 63.0) - 0.5f;
    const float y0f = floorf(ys);
    const float ty  = ys - y0f;
    const int   y0  = (int)y0f;
    const int   y1  = y0 + 1;
    const float vy0 = (y0 >= 0 && y0 < HH) ? 1.f : 0.f;
    const float vy1 = (y1 >= 0 && y1 < HH) ? 1.f : 0.f;
    const int   y0c = min(max(y0, 0), HH - 1);
    const int   y1c = min(max(y1, 0), HH - 1);
    const float ey0 = (1.f - ty) * vy0;
    const float ey1 = ty * vy1;
    const float eysum = ey0 + ey1;

    __shared__ uint16_t Yc[192 * 68];   // 26,112 B: combined row, [x][c] stride 68
    __shared__ uint16_t Pt[96 * 196];   // 37,632 B: [w_half_local][x] stride 196

    const int tid  = threadIdx.x;
    const int wave = tid >> 6;
    const int lane = tid & 63;
    const int lq   = lane >> 4;    // quad 0..3
    const int ln   = lane & 15;

    // ---- stage Yc once: wave = c-group (16 groups of 4c), x = k*64+lane ----
    const float* Yb0 = Yv + ((size_t)b * CC * HH + y0c) * WW;
    const float* Yb1 = Yv + ((size_t)b * CC * HH + y1c) * WW;
#pragma unroll
    for (int k = 0; k < 3; k++) {
        const int cg = wave;
        const int xx = k * 64 + lane;
        uint32_t pk[2];
#pragma unroll
        for (int half = 0; half < 2; half++) {
            uint32_t pv = 0;
#pragma unroll
            for (int j = 0; j < 2; j++) {
                const int c = cg * 4 + half * 2 + j;
                const float v0 = Yb0[(size_t)c * HH * WW + xx];
                const float v1 = Yb1[(size_t)c * HH * WW + xx];
                const float cb = fmaf(ey1, v1, ey0 * v0);
                pv |= ((uint32_t)f2bf(cb)) << (16 * j);
            }
            pk[half] = pv;
        }
        *reinterpret_cast<uint2*>(&Yc[xx * 68 + cg * 4]) = *reinterpret_cast<uint2*>(pk);
    }
    __syncthreads();

    const float cx = (float)(192.0 / 191.0);
    const float inv_c = 1.f / 64.f;

    for (int half = 0; half < 2; half++) {
        // ---- MFMA: 6 m-chunks x 12 n-tiles; waves 0..11 do 6 tiles each ----
        if (wave < 12) {
            const int mcl = wave >> 1;                    // local m-chunk 0..5
            const uint16_t* ar = Ab + (size_t)(half * 96 + mcl * 16 + ln) * CC + lq * 8;
            short8 a0 = *reinterpret_cast<const short8*>(ar);
            short8 a1 = *reinterpret_cast<const short8*>(ar + 32);
#pragma unroll
            for (int i = 0; i < 6; i++) {
                const int nt = (wave & 1) * 6 + i;
                const int Rb = nt * 16;
                const uint16_t* yrow = &Yc[(Rb + ln) * 68 + lq * 8];
                short8 b0, b1;
                *reinterpret_cast<uint2*>(&b0)       = *reinterpret_cast<const uint2*>(yrow);
                *(reinterpret_cast<uint2*>(&b0) + 1) = *reinterpret_cast<const uint2*>(yrow + 4);
                *reinterpret_cast<uint2*>(&b1)       = *reinterpret_cast<const uint2*>(yrow + 32);
                *(reinterpret_cast<uint2*>(&b1) + 1) = *reinterpret_cast<const uint2*>(yrow + 36);
                floatx4 acc = {0.f, 0.f, 0.f, 0.f};
                acc = __builtin_amdgcn_mfma_f32_16x16x32_bf16(a0, b0, acc, 0, 0, 0);
                acc = __builtin_amdgcn_mfma_f32_16x16x32_bf16(a1, b1, acc, 0, 0, 0);
                // C layout: col(N)=ln -> x' ; row(M)=lq*4+reg -> w_local
                const int pcol = Rb + ln;
                const int wl   = mcl * 16 + lq * 4;
                Pt[(wl + 0) * 196 + pcol] = f2bf(acc[0]);
                Pt[(wl + 1) * 196 + pcol] = f2bf(acc[1]);
                Pt[(wl + 2) * 196 + pcol] = f2bf(acc[2]);
                Pt[(wl + 3) * 196 + pcol] = f2bf(acc[3]);
            }
        }
        __syncthreads();

        // ---- epilogue: 96 w x 24 d outputs ----
        for (int o = tid; o < 96 * DD; o += 1024) {
            const int wl = o % 96;           // local w within half
            const int d  = o / 96;
            const int w  = half * 96 + wl;
            const float dsv = disp[((size_t)(b * DD + d) * HH + h) * WW + w];
            const float xs  = dsv * cx - 0.5f;
            const float x0f = floorf(xs);
            const float tx  = xs - x0f;
            const int   x0  = (int)x0f;
            const int   x1  = x0 + 1;
            const float vx0 = (x0 >= 0 && x0 < WW) ? 1.f : 0.f;
            const float vx1 = (x1 >= 0 && x1 < WW) ? 1.f : 0.f;
            const int   x0c = min(max(x0, 0), WW - 1);
            const int   x1c = min(max(x1, 0), WW - 1);
            const float wx0 = (1.f - tx) * vx0;
            const float wx1 = tx * vx1;
            const float pc0 = bf1(Pt[wl * 196 + x0c]);
            const float pc1 = bf1(Pt[wl * 196 + x1c]);
            const float res = wx0 * pc0 + wx1 * pc1 + sb[w] * (eysum * (wx0 + wx1));
            out[(((size_t)(v * BB + b) * DD + d) * HH + h) * WW + w] = res * inv_c;
        }
        __syncthreads();   // protect Pt before next half's MFMA writes
    }
}

// =====================================================================
extern "C" void kernel_launch(void* const* d_in, const int* in_sizes, int n_in,
                              void* d_out, int out_size, void* d_ws, size_t ws_size,
                              hipStream_t stream) {
    const float* x  = (const float*)d_in[0];
    const float* y  = (const float*)d_in[1];
    const float* d1 = (const float*)d_in[2];
    const float* d2 = (const float*)d_in[3];
    // d_in[4] = ndisp (int32) — compile-time DD=24
    const float* qw = (const float*)d_in[5];
    const float* qb = (const float*)d_in[6];
    const float* kw = (const float*)d_in[7];
    const float* kb = (const float*)d_in[8];

    uint16_t* A   = (uint16_t*)d_ws;
    float*    fws = (float*)((uint16_t*)d_ws + A_SHORTS);
    float*    out = (float*)d_out;

    prep_kernel<<<dim3(66), dim3(64), 0, stream>>>(qw, qb, kw, kb, fws);
    convA_kernel<<<dim3(PIX / 256, 2), dim3(64, 4), 0, stream>>>(x, y, fws, A);
    cost_kernel<<<dim3(HH, BB, 2), dim3(1024), 0, stream>>>(x, y, d1, d2, A, fws, out);
}